// Round 1
// baseline (250.477 us; speedup 1.0000x reference)
//
#include <hip/hip_runtime.h>

#define D_FEAT 128
#define WAVE 64

__device__ __forceinline__ int lower_bound_i(const int* __restrict__ a, int n, int key) {
    int lo = 0, hi = n;
    while (lo < hi) {
        int mid = (lo + hi) >> 1;
        if (a[mid] < key) lo = mid + 1; else hi = mid;
    }
    return lo;
}

// One wave per output row. row_ids is sorted, so each row's edges are a
// contiguous range found by binary search. 64 lanes x float2 = 128 floats/row,
// coalesced 512B per edge gather.
__global__ void mean_agg_kernel(const float* __restrict__ feats,
                                const int* __restrict__ nids,
                                const int* __restrict__ rids,
                                float* __restrict__ out,
                                int n_edges, int n_rows) {
    int gtid = blockIdx.x * blockDim.x + threadIdx.x;
    int wave = gtid / WAVE;
    int lane = threadIdx.x & (WAVE - 1);
    if (wave >= n_rows) return;

    const int row = wave;
    // wave-uniform binary searches (compiler scalarizes; all lanes redundant)
    int lo = lower_bound_i(rids, n_edges, row);
    int hi = lower_bound_i(rids, n_edges, row + 1);

    float2 acc = make_float2(0.0f, 0.0f);

    int e = lo;
    // 4-way unroll: 4 independent gathers in flight
    for (; e + 3 < hi; e += 4) {
        int n0 = nids[e + 0];
        int n1 = nids[e + 1];
        int n2 = nids[e + 2];
        int n3 = nids[e + 3];
        const float2* f0 = (const float2*)(feats + (size_t)n0 * D_FEAT);
        const float2* f1 = (const float2*)(feats + (size_t)n1 * D_FEAT);
        const float2* f2 = (const float2*)(feats + (size_t)n2 * D_FEAT);
        const float2* f3 = (const float2*)(feats + (size_t)n3 * D_FEAT);
        float2 v0 = f0[lane];
        float2 v1 = f1[lane];
        float2 v2 = f2[lane];
        float2 v3 = f3[lane];
        acc.x += v0.x + v1.x + v2.x + v3.x;
        acc.y += v0.y + v1.y + v2.y + v3.y;
    }
    for (; e < hi; ++e) {
        int n0 = nids[e];
        const float2* f0 = (const float2*)(feats + (size_t)n0 * D_FEAT);
        float2 v0 = f0[lane];
        acc.x += v0.x;
        acc.y += v0.y;
    }

    int deg = hi - lo;
    float cnt = (float)(deg > 0 ? deg : 1);
    float2 o;
    o.x = acc.x / cnt;
    o.y = acc.y / cnt;
    ((float2*)(out + (size_t)row * D_FEAT))[lane] = o;
}

extern "C" void kernel_launch(void* const* d_in, const int* in_sizes, int n_in,
                              void* d_out, int out_size, void* d_ws, size_t ws_size,
                              hipStream_t stream) {
    const float* feats = (const float*)d_in[0];
    const int* nids    = (const int*)d_in[1];
    const int* rids    = (const int*)d_in[2];
    float* out         = (float*)d_out;

    int n_edges = in_sizes[1];
    int n_rows  = out_size / D_FEAT;

    const int BLOCK = 256;                 // 4 waves/block
    int waves_per_block = BLOCK / WAVE;
    int grid = (n_rows + waves_per_block - 1) / waves_per_block;

    mean_agg_kernel<<<grid, BLOCK, 0, stream>>>(feats, nids, rids, out, n_edges, n_rows);
}

// Round 2
// 233.116 us; speedup vs baseline: 1.0745x; 1.0745x over previous
//
#include <hip/hip_runtime.h>

#define D_FEAT 128
#define WAVE 64

__device__ __forceinline__ int lower_bound_i(const int* __restrict__ a, int n, int key) {
    int lo = 0, hi = n;
    while (lo < hi) {
        int mid = (lo + hi) >> 1;
        if (a[mid] < key) lo = mid + 1; else hi = mid;
    }
    return lo;
}

// One wave per output row. row_ids sorted -> contiguous edge range per row.
// float4/lane, half-wave pairing: lanes 0-31 handle edge e, lanes 32-63 edge
// e+1 -> one wave64 load instruction gathers TWO 512B feature rows (1 KiB).
// 4-deep unroll = 8 edges / 4 KiB in flight per wave.
__global__ void mean_agg_kernel(const float* __restrict__ feats,
                                const int* __restrict__ nids,
                                const int* __restrict__ rids,
                                float* __restrict__ out,
                                int n_edges, int n_rows) {
    int gtid = blockIdx.x * blockDim.x + threadIdx.x;
    int wave = gtid / WAVE;
    int lane = threadIdx.x & (WAVE - 1);
    if (wave >= n_rows) return;

    const int row  = wave;
    const int half = lane >> 5;        // 0: even edge, 1: odd edge
    const int sub  = lane & 31;        // float4 slot within the 128-float row

    int lo = lower_bound_i(rids, n_edges, row);
    int hi = lower_bound_i(rids, n_edges, row + 1);

    float4 acc = make_float4(0.f, 0.f, 0.f, 0.f);

    int e = lo;
    // main loop: 8 edges (4 paired wave-loads) per iteration
    for (; e + 8 <= hi; e += 8) {
        int i0 = nids[e + 0 + half];
        int i1 = nids[e + 2 + half];
        int i2 = nids[e + 4 + half];
        int i3 = nids[e + 6 + half];
        float4 v0 = ((const float4*)(feats + (size_t)i0 * D_FEAT))[sub];
        float4 v1 = ((const float4*)(feats + (size_t)i1 * D_FEAT))[sub];
        float4 v2 = ((const float4*)(feats + (size_t)i2 * D_FEAT))[sub];
        float4 v3 = ((const float4*)(feats + (size_t)i3 * D_FEAT))[sub];
        acc.x += v0.x + v1.x + v2.x + v3.x;
        acc.y += v0.y + v1.y + v2.y + v3.y;
        acc.z += v0.z + v1.z + v2.z + v3.z;
        acc.w += v0.w + v1.w + v2.w + v3.w;
    }
    // pair remainder: 2 edges per iteration
    for (; e + 2 <= hi; e += 2) {
        int i0 = nids[e + half];
        float4 v0 = ((const float4*)(feats + (size_t)i0 * D_FEAT))[sub];
        acc.x += v0.x; acc.y += v0.y; acc.z += v0.z; acc.w += v0.w;
    }
    // odd tail: only the low half-wave reads the last edge
    if (e < hi && half == 0) {
        int i0 = nids[e];
        float4 v0 = ((const float4*)(feats + (size_t)i0 * D_FEAT))[sub];
        acc.x += v0.x; acc.y += v0.y; acc.z += v0.z; acc.w += v0.w;
    }

    // fold the two half-wave accumulators (lane L += lane L^32)
    acc.x += __shfl_xor(acc.x, 32, WAVE);
    acc.y += __shfl_xor(acc.y, 32, WAVE);
    acc.z += __shfl_xor(acc.z, 32, WAVE);
    acc.w += __shfl_xor(acc.w, 32, WAVE);

    int deg = hi - lo;
    float inv = 1.0f / (float)(deg > 0 ? deg : 1);
    if (half == 0) {
        float4 o;
        o.x = acc.x * inv; o.y = acc.y * inv; o.z = acc.z * inv; o.w = acc.w * inv;
        ((float4*)(out + (size_t)row * D_FEAT))[sub] = o;
    }
}

extern "C" void kernel_launch(void* const* d_in, const int* in_sizes, int n_in,
                              void* d_out, int out_size, void* d_ws, size_t ws_size,
                              hipStream_t stream) {
    const float* feats = (const float*)d_in[0];
    const int* nids    = (const int*)d_in[1];
    const int* rids    = (const int*)d_in[2];
    float* out         = (float*)d_out;

    int n_edges = in_sizes[1];
    int n_rows  = out_size / D_FEAT;

    const int BLOCK = 256;                 // 4 waves/block
    int waves_per_block = BLOCK / WAVE;
    int grid = (n_rows + waves_per_block - 1) / waves_per_block;

    mean_agg_kernel<<<grid, BLOCK, 0, stream>>>(feats, nids, rids, out, n_edges, n_rows);
}

// Round 3
// 201.527 us; speedup vs baseline: 1.2429x; 1.1567x over previous
//
#include <hip/hip_runtime.h>

#define D_FEAT 128
#define WAVE 64

// Kernel 1: CSR row-offset build from sorted row_ids.
// row_start[r] = first edge with rids[e] >= r, for r in [0, n_rows].
// Each thread handles the boundary at edge e; gap loop fills empty rows.
__global__ void build_row_start(const int* __restrict__ rids,
                                int* __restrict__ row_start,
                                int n_edges, int n_rows) {
    int e = blockIdx.x * blockDim.x + threadIdx.x;
    if (e >= n_edges) return;
    int r_cur  = rids[e];
    int r_prev = (e == 0) ? -1 : rids[e - 1];
    for (int r = r_prev + 1; r <= r_cur; ++r) row_start[r] = e;
    if (e == n_edges - 1) {
        for (int r = r_cur + 1; r <= n_rows; ++r) row_start[r] = n_edges;
    }
}

// Kernel 2: one wave per output row. float4/lane, half-wave pairing:
// lanes 0-31 handle edge e, lanes 32-63 edge e+1 -> one wave64 load gathers
// TWO 512B feature rows. 8 independent paired loads (16 edges) in flight.
__global__ void mean_agg_kernel(const float* __restrict__ feats,
                                const int* __restrict__ nids,
                                const int* __restrict__ row_start,
                                float* __restrict__ out,
                                int n_rows) {
    int gtid = blockIdx.x * blockDim.x + threadIdx.x;
    int wave = gtid / WAVE;
    int lane = threadIdx.x & (WAVE - 1);
    if (wave >= n_rows) return;

    const int row  = wave;
    const int half = lane >> 5;        // 0: even edge, 1: odd edge
    const int sub  = lane & 31;        // float4 slot within the 128-float row

    int lo = row_start[row];
    int hi = row_start[row + 1];

    float4 acc = make_float4(0.f, 0.f, 0.f, 0.f);

    int e = lo;
    // main loop: 16 edges (8 paired wave-loads, all independent) per iteration
    for (; e + 16 <= hi; e += 16) {
        int i0 = nids[e +  0 + half];
        int i1 = nids[e +  2 + half];
        int i2 = nids[e +  4 + half];
        int i3 = nids[e +  6 + half];
        int i4 = nids[e +  8 + half];
        int i5 = nids[e + 10 + half];
        int i6 = nids[e + 12 + half];
        int i7 = nids[e + 14 + half];
        float4 v0 = ((const float4*)(feats + (size_t)i0 * D_FEAT))[sub];
        float4 v1 = ((const float4*)(feats + (size_t)i1 * D_FEAT))[sub];
        float4 v2 = ((const float4*)(feats + (size_t)i2 * D_FEAT))[sub];
        float4 v3 = ((const float4*)(feats + (size_t)i3 * D_FEAT))[sub];
        float4 v4 = ((const float4*)(feats + (size_t)i4 * D_FEAT))[sub];
        float4 v5 = ((const float4*)(feats + (size_t)i5 * D_FEAT))[sub];
        float4 v6 = ((const float4*)(feats + (size_t)i6 * D_FEAT))[sub];
        float4 v7 = ((const float4*)(feats + (size_t)i7 * D_FEAT))[sub];
        acc.x += v0.x + v1.x + v2.x + v3.x + v4.x + v5.x + v6.x + v7.x;
        acc.y += v0.y + v1.y + v2.y + v3.y + v4.y + v5.y + v6.y + v7.y;
        acc.z += v0.z + v1.z + v2.z + v3.z + v4.z + v5.z + v6.z + v7.z;
        acc.w += v0.w + v1.w + v2.w + v3.w + v4.w + v5.w + v6.w + v7.w;
    }
    // 8-edge step
    for (; e + 8 <= hi; e += 8) {
        int i0 = nids[e + 0 + half];
        int i1 = nids[e + 2 + half];
        int i2 = nids[e + 4 + half];
        int i3 = nids[e + 6 + half];
        float4 v0 = ((const float4*)(feats + (size_t)i0 * D_FEAT))[sub];
        float4 v1 = ((const float4*)(feats + (size_t)i1 * D_FEAT))[sub];
        float4 v2 = ((const float4*)(feats + (size_t)i2 * D_FEAT))[sub];
        float4 v3 = ((const float4*)(feats + (size_t)i3 * D_FEAT))[sub];
        acc.x += v0.x + v1.x + v2.x + v3.x;
        acc.y += v0.y + v1.y + v2.y + v3.y;
        acc.z += v0.z + v1.z + v2.z + v3.z;
        acc.w += v0.w + v1.w + v2.w + v3.w;
    }
    // pair remainder
    for (; e + 2 <= hi; e += 2) {
        int i0 = nids[e + half];
        float4 v0 = ((const float4*)(feats + (size_t)i0 * D_FEAT))[sub];
        acc.x += v0.x; acc.y += v0.y; acc.z += v0.z; acc.w += v0.w;
    }
    // odd tail: only the low half-wave reads the last edge
    if (e < hi && half == 0) {
        int i0 = nids[e];
        float4 v0 = ((const float4*)(feats + (size_t)i0 * D_FEAT))[sub];
        acc.x += v0.x; acc.y += v0.y; acc.z += v0.z; acc.w += v0.w;
    }

    // fold the two half-wave accumulators (lane L += lane L^32)
    acc.x += __shfl_xor(acc.x, 32, WAVE);
    acc.y += __shfl_xor(acc.y, 32, WAVE);
    acc.z += __shfl_xor(acc.z, 32, WAVE);
    acc.w += __shfl_xor(acc.w, 32, WAVE);

    int deg = hi - lo;
    float inv = 1.0f / (float)(deg > 0 ? deg : 1);
    if (half == 0) {
        float4 o;
        o.x = acc.x * inv; o.y = acc.y * inv; o.z = acc.z * inv; o.w = acc.w * inv;
        ((float4*)(out + (size_t)row * D_FEAT))[sub] = o;
    }
}

extern "C" void kernel_launch(void* const* d_in, const int* in_sizes, int n_in,
                              void* d_out, int out_size, void* d_ws, size_t ws_size,
                              hipStream_t stream) {
    const float* feats = (const float*)d_in[0];
    const int* nids    = (const int*)d_in[1];
    const int* rids    = (const int*)d_in[2];
    float* out         = (float*)d_out;

    int n_edges = in_sizes[1];
    int n_rows  = out_size / D_FEAT;

    int* row_start = (int*)d_ws;   // (n_rows + 1) ints = ~200 KB

    const int BLOCK = 256;
    int grid1 = (n_edges + BLOCK - 1) / BLOCK;
    build_row_start<<<grid1, BLOCK, 0, stream>>>(rids, row_start, n_edges, n_rows);

    int waves_per_block = BLOCK / WAVE;
    int grid2 = (n_rows + waves_per_block - 1) / waves_per_block;
    mean_agg_kernel<<<grid2, BLOCK, 0, stream>>>(feats, nids, row_start, out, n_rows);
}

// Round 4
// 170.455 us; speedup vs baseline: 1.4695x; 1.1823x over previous
//
#include <hip/hip_runtime.h>

#define D_FEAT 128
#define WAVE 64

__device__ __forceinline__ unsigned short f32_to_bf16_rn(float f) {
    unsigned int u = __float_as_uint(f);
    unsigned int r = u + 0x7fffu + ((u >> 16) & 1u);   // round-to-nearest-even
    return (unsigned short)(r >> 16);
}

// Kernel 1: CSR row-offset build from sorted row_ids.
__global__ void build_row_start(const int* __restrict__ rids,
                                int* __restrict__ row_start,
                                int n_edges, int n_rows) {
    int e = blockIdx.x * blockDim.x + threadIdx.x;
    if (e >= n_edges) return;
    int r_cur  = rids[e];
    int r_prev = (e == 0) ? -1 : rids[e - 1];
    for (int r = r_prev + 1; r <= r_cur; ++r) row_start[r] = e;
    if (e == n_edges - 1) {
        for (int r = r_cur + 1; r <= n_rows; ++r) row_start[r] = n_edges;
    }
}

// Kernel 2: fp32 features -> bf16 table in d_ws, plus one appended zero row
// (index n_nodes) used by predicated-invalid lanes in the gather.
__global__ void convert_bf16(const float* __restrict__ feats,
                             unsigned short* __restrict__ tbl,
                             int n_elems, int total) {
    int i = (blockIdx.x * blockDim.x + threadIdx.x) * 4;
    if (i >= total) return;
    if (i + 4 <= n_elems) {
        float4 v = *(const float4*)(feats + i);
        ushort4 o;
        o.x = f32_to_bf16_rn(v.x);
        o.y = f32_to_bf16_rn(v.y);
        o.z = f32_to_bf16_rn(v.z);
        o.w = f32_to_bf16_rn(v.w);
        *(ushort4*)(tbl + i) = o;
    } else {
        for (int k = 0; k < 4 && i + k < total; ++k)
            tbl[i + k] = (i + k < n_elems) ? f32_to_bf16_rn(feats[i + k])
                                           : (unsigned short)0;
    }
}

// Kernel 3: one wave per output row. bf16 row = 256 B -> quarter-wave
// (16 lanes x 16 B) per edge; one wave64 load gathers FOUR rows (1 KiB).
// 8 unrolled groups = 32 edges (the average degree) in flight per iteration.
__global__ void mean_agg_kernel(const unsigned short* __restrict__ tbl,
                                const int* __restrict__ nids,
                                const int* __restrict__ row_start,
                                float* __restrict__ out,
                                int n_rows, int zero_row) {
    int wave = (blockIdx.x * blockDim.x + threadIdx.x) / WAVE;
    int lane = threadIdx.x & (WAVE - 1);
    if (wave >= n_rows) return;

    const int q   = lane >> 4;     // quarter 0..3 -> which edge of the group
    const int sub = lane & 15;     // 8-element slot within the 128-elem row

    int lo = row_start[wave];
    int hi = row_start[wave + 1];

    float acc[8];
    #pragma unroll
    for (int k = 0; k < 8; ++k) acc[k] = 0.f;

    int e = lo;
    // main loop: 32 edges (8 quarter-wave groups, all independent) per iter
    for (; e + 32 <= hi; e += 32) {
        uint4 u[8];
        #pragma unroll
        for (int g = 0; g < 8; ++g) {
            int nid = nids[e + 4 * g + q];
            u[g] = *(const uint4*)(tbl + (size_t)nid * D_FEAT + sub * 8);
        }
        #pragma unroll
        for (int g = 0; g < 8; ++g) {
            acc[0] += __uint_as_float(u[g].x << 16);
            acc[1] += __uint_as_float(u[g].x & 0xffff0000u);
            acc[2] += __uint_as_float(u[g].y << 16);
            acc[3] += __uint_as_float(u[g].y & 0xffff0000u);
            acc[4] += __uint_as_float(u[g].z << 16);
            acc[5] += __uint_as_float(u[g].z & 0xffff0000u);
            acc[6] += __uint_as_float(u[g].w << 16);
            acc[7] += __uint_as_float(u[g].w & 0xffff0000u);
        }
    }
    // tail (<32 edges): wave-uniform skip per group; ragged lanes hit zero row
    #pragma unroll
    for (int g = 0; g < 8; ++g) {
        int base = e + 4 * g;
        if (base < hi) {
            int idx = base + q;
            int nid = (idx < hi) ? nids[idx] : zero_row;
            uint4 u = *(const uint4*)(tbl + (size_t)nid * D_FEAT + sub * 8);
            acc[0] += __uint_as_float(u.x << 16);
            acc[1] += __uint_as_float(u.x & 0xffff0000u);
            acc[2] += __uint_as_float(u.y << 16);
            acc[3] += __uint_as_float(u.y & 0xffff0000u);
            acc[4] += __uint_as_float(u.z << 16);
            acc[5] += __uint_as_float(u.z & 0xffff0000u);
            acc[6] += __uint_as_float(u.w << 16);
            acc[7] += __uint_as_float(u.w & 0xffff0000u);
        }
    }

    // fold the four quarter-wave accumulators (xor 16, then 32)
    #pragma unroll
    for (int k = 0; k < 8; ++k) {
        acc[k] += __shfl_xor(acc[k], 16, WAVE);
        acc[k] += __shfl_xor(acc[k], 32, WAVE);
    }

    int deg = hi - lo;
    float inv = 1.0f / (float)(deg > 0 ? deg : 1);
    if (q == 0) {
        float* dst = out + (size_t)wave * D_FEAT + sub * 8;
        float4 o0 = make_float4(acc[0] * inv, acc[1] * inv, acc[2] * inv, acc[3] * inv);
        float4 o1 = make_float4(acc[4] * inv, acc[5] * inv, acc[6] * inv, acc[7] * inv);
        *(float4*)dst = o0;
        *(float4*)(dst + 4) = o1;
    }
}

extern "C" void kernel_launch(void* const* d_in, const int* in_sizes, int n_in,
                              void* d_out, int out_size, void* d_ws, size_t ws_size,
                              hipStream_t stream) {
    const float* feats = (const float*)d_in[0];
    const int* nids    = (const int*)d_in[1];
    const int* rids    = (const int*)d_in[2];
    float* out         = (float*)d_out;

    int n_feat_elems = in_sizes[0];
    int n_nodes      = n_feat_elems / D_FEAT;
    int n_edges      = in_sizes[1];
    int n_rows       = out_size / D_FEAT;

    // ws layout: [bf16 table, (n_nodes+1) rows incl. zero row][row_start]
    unsigned short* tbl = (unsigned short*)d_ws;
    size_t tbl_bytes = (size_t)(n_nodes + 1) * D_FEAT * sizeof(unsigned short);
    tbl_bytes = (tbl_bytes + 255) & ~(size_t)255;
    int* row_start = (int*)((char*)d_ws + tbl_bytes);

    const int BLOCK = 256;

    int total_tbl = (n_nodes + 1) * D_FEAT;
    int grid_c = (total_tbl / 4 + BLOCK - 1) / BLOCK;
    convert_bf16<<<grid_c, BLOCK, 0, stream>>>(feats, tbl, n_feat_elems, total_tbl);

    int grid_b = (n_edges + BLOCK - 1) / BLOCK;
    build_row_start<<<grid_b, BLOCK, 0, stream>>>(rids, row_start, n_edges, n_rows);

    int waves_per_block = BLOCK / WAVE;
    int grid_a = (n_rows + waves_per_block - 1) / waves_per_block;
    mean_agg_kernel<<<grid_a, BLOCK, 0, stream>>>(tbl, nids, row_start, out,
                                                  n_rows, n_nodes);
}

// Round 5
// 156.338 us; speedup vs baseline: 1.6021x; 1.0903x over previous
//
#include <hip/hip_runtime.h>

#define D_FEAT 128
#define WAVE 64

__device__ __forceinline__ unsigned short f32_to_bf16_rn(float f) {
    unsigned int u = __float_as_uint(f);
    unsigned int r = u + 0x7fffu + ((u >> 16) & 1u);   // round-to-nearest-even
    return (unsigned short)(r >> 16);
}

// Kernel 1: CSR row-offset build from sorted row_ids.
__global__ void build_row_start(const int* __restrict__ rids,
                                int* __restrict__ row_start,
                                int n_edges, int n_rows) {
    int e = blockIdx.x * blockDim.x + threadIdx.x;
    if (e >= n_edges) return;
    int r_cur  = rids[e];
    int r_prev = (e == 0) ? -1 : rids[e - 1];
    for (int r = r_prev + 1; r <= r_cur; ++r) row_start[r] = e;
    if (e == n_edges - 1) {
        for (int r = r_cur + 1; r <= n_rows; ++r) row_start[r] = n_edges;
    }
}

// Kernel 2: fp32 features -> bf16 table in d_ws (8 elems/thread), plus one
// appended zero row (index n_nodes) used by clamped-invalid lanes.
__global__ void convert_bf16(const float* __restrict__ feats,
                             unsigned short* __restrict__ tbl,
                             int n_elems, int total) {
    int i = (blockIdx.x * blockDim.x + threadIdx.x) * 8;
    if (i >= total) return;
    if (i + 8 <= n_elems) {
        float4 a = *(const float4*)(feats + i);
        float4 b = *(const float4*)(feats + i + 4);
        uint4 o;
        o.x = (unsigned)f32_to_bf16_rn(a.x) | ((unsigned)f32_to_bf16_rn(a.y) << 16);
        o.y = (unsigned)f32_to_bf16_rn(a.z) | ((unsigned)f32_to_bf16_rn(a.w) << 16);
        o.z = (unsigned)f32_to_bf16_rn(b.x) | ((unsigned)f32_to_bf16_rn(b.y) << 16);
        o.w = (unsigned)f32_to_bf16_rn(b.z) | ((unsigned)f32_to_bf16_rn(b.w) << 16);
        *(uint4*)(tbl + i) = o;
    } else {
        for (int k = 0; k < 8 && i + k < total; ++k)
            tbl[i + k] = (i + k < n_elems) ? f32_to_bf16_rn(feats[i + k])
                                           : (unsigned short)0;
    }
}

// Kernel 3: one wave per output row. bf16 row = 256 B -> quarter-wave
// (16 lanes x 16 B) per edge; one wave64 load gathers FOUR rows.
// Branch-free clamped loop, step 16 (4 independent gathers / iter).
// 32-bit uint4 table indices -> SGPR-base + VGPR-offset addressing.
__global__ void __launch_bounds__(256)
mean_agg_kernel(const uint4* __restrict__ tbl4,
                const int* __restrict__ nids,
                const int* __restrict__ row_start,
                float* __restrict__ out,
                int n_rows, int zero_row) {
    int wave = (blockIdx.x * blockDim.x + threadIdx.x) >> 6;
    int lane = threadIdx.x & (WAVE - 1);
    if (wave >= n_rows) return;

    const int q   = lane >> 4;     // quarter 0..3 -> which edge of a group of 4
    const int sub = lane & 15;     // uint4 slot within the 256 B row

    int lo = row_start[wave];
    int hi = row_start[wave + 1];

    float acc[8];
    #pragma unroll
    for (int k = 0; k < 8; ++k) acc[k] = 0.f;

    for (int e = lo; e < hi; e += 16) {
        #pragma unroll
        for (int g = 0; g < 4; ++g) {
            int idx = e + 4 * g + q;
            int idc = idx < hi ? idx : hi - 1;       // safe: loop entered => hi > lo >= 0
            int nid = nids[idc];
            nid = idx < hi ? nid : zero_row;          // padded lanes hit zero row
            unsigned off = ((unsigned)nid << 4) + (unsigned)sub;
            uint4 u = tbl4[off];
            acc[0] += __uint_as_float(u.x << 16);
            acc[1] += __uint_as_float(u.x & 0xffff0000u);
            acc[2] += __uint_as_float(u.y << 16);
            acc[3] += __uint_as_float(u.y & 0xffff0000u);
            acc[4] += __uint_as_float(u.z << 16);
            acc[5] += __uint_as_float(u.z & 0xffff0000u);
            acc[6] += __uint_as_float(u.w << 16);
            acc[7] += __uint_as_float(u.w & 0xffff0000u);
        }
    }

    // fold the four quarter-wave accumulators (xor 16, then 32)
    #pragma unroll
    for (int k = 0; k < 8; ++k) {
        acc[k] += __shfl_xor(acc[k], 16, WAVE);
        acc[k] += __shfl_xor(acc[k], 32, WAVE);
    }

    int deg = hi - lo;
    float inv = 1.0f / (float)(deg > 0 ? deg : 1);

    // lanes 0-31 each store one float4 -> one coalesced 512 B row write
    if (q < 2) {
        float4 o;
        o.x = (q == 0 ? acc[0] : acc[4]) * inv;
        o.y = (q == 0 ? acc[1] : acc[5]) * inv;
        o.z = (q == 0 ? acc[2] : acc[6]) * inv;
        o.w = (q == 0 ? acc[3] : acc[7]) * inv;
        *(float4*)(out + (size_t)wave * D_FEAT + sub * 8 + q * 4) = o;
    }
}

extern "C" void kernel_launch(void* const* d_in, const int* in_sizes, int n_in,
                              void* d_out, int out_size, void* d_ws, size_t ws_size,
                              hipStream_t stream) {
    const float* feats = (const float*)d_in[0];
    const int* nids    = (const int*)d_in[1];
    const int* rids    = (const int*)d_in[2];
    float* out         = (float*)d_out;

    int n_feat_elems = in_sizes[0];
    int n_nodes      = n_feat_elems / D_FEAT;
    int n_edges      = in_sizes[1];
    int n_rows       = out_size / D_FEAT;

    // ws layout: [bf16 table, (n_nodes+1) rows incl. zero row][row_start]
    unsigned short* tbl = (unsigned short*)d_ws;
    size_t tbl_bytes = (size_t)(n_nodes + 1) * D_FEAT * sizeof(unsigned short);
    tbl_bytes = (tbl_bytes + 255) & ~(size_t)255;
    int* row_start = (int*)((char*)d_ws + tbl_bytes);

    const int BLOCK = 256;

    int total_tbl = (n_nodes + 1) * D_FEAT;
    int grid_c = ((total_tbl + 7) / 8 + BLOCK - 1) / BLOCK;
    convert_bf16<<<grid_c, BLOCK, 0, stream>>>(feats, tbl, n_feat_elems, total_tbl);

    int grid_b = (n_edges + BLOCK - 1) / BLOCK;
    build_row_start<<<grid_b, BLOCK, 0, stream>>>(rids, row_start, n_edges, n_rows);

    int waves_per_block = BLOCK / WAVE;
    int grid_a = (n_rows + waves_per_block - 1) / waves_per_block;
    mean_agg_kernel<<<grid_a, BLOCK, 0, stream>>>((const uint4*)tbl, nids, row_start,
                                                  out, n_rows, n_nodes);
}

// Round 7
// 153.716 us; speedup vs baseline: 1.6295x; 1.0171x over previous
//
#include <hip/hip_runtime.h>

#define D_FEAT 128
#define WAVE 64

__device__ __forceinline__ unsigned short f32_to_bf16_rn(float f) {
    unsigned int u = __float_as_uint(f);
    unsigned int r = u + 0x7fffu + ((u >> 16) & 1u);   // round-to-nearest-even
    return (unsigned short)(r >> 16);
}

// Fused pre-pass: blocks [0, grid_c) convert fp32->bf16 table (8 elems/thread,
// plus appended zero row at index n_nodes); blocks [grid_c, grid_c+grid_b)
// build CSR row offsets from the sorted row_ids.
__global__ void prep_kernel(const float* __restrict__ feats,
                            unsigned short* __restrict__ tbl,
                            int n_elems, int total,
                            const int* __restrict__ rids,
                            int* __restrict__ row_start,
                            int n_edges, int n_rows, int grid_c) {
    if ((int)blockIdx.x < grid_c) {
        int i = (blockIdx.x * blockDim.x + threadIdx.x) * 8;
        if (i >= total) return;
        if (i + 8 <= n_elems) {
            float4 a = *(const float4*)(feats + i);
            float4 b = *(const float4*)(feats + i + 4);
            uint4 o;
            o.x = (unsigned)f32_to_bf16_rn(a.x) | ((unsigned)f32_to_bf16_rn(a.y) << 16);
            o.y = (unsigned)f32_to_bf16_rn(a.z) | ((unsigned)f32_to_bf16_rn(a.w) << 16);
            o.z = (unsigned)f32_to_bf16_rn(b.x) | ((unsigned)f32_to_bf16_rn(b.y) << 16);
            o.w = (unsigned)f32_to_bf16_rn(b.z) | ((unsigned)f32_to_bf16_rn(b.w) << 16);
            *(uint4*)(tbl + i) = o;
        } else {
            for (int k = 0; k < 8 && i + k < total; ++k)
                tbl[i + k] = (i + k < n_elems) ? f32_to_bf16_rn(feats[i + k])
                                               : (unsigned short)0;
        }
    } else {
        int e = (blockIdx.x - grid_c) * blockDim.x + threadIdx.x;
        if (e >= n_edges) return;
        int r_cur  = rids[e];
        int r_prev = (e == 0) ? -1 : rids[e - 1];
        for (int r = r_prev + 1; r <= r_cur; ++r) row_start[r] = e;
        if (e == n_edges - 1) {
            for (int r = r_cur + 1; r <= n_rows; ++r) row_start[r] = n_edges;
        }
    }
}

// One wave per output row. bf16 row = 256 B -> quarter-wave (16 lanes x 16 B)
// per edge; one wave64 load gathers FOUR rows. Full loop (step 32): ids come
// from ONE wave load + __shfl -> 8 unpredicated gathers issue back-to-back
// (8 KB in flight/wave). Remainder: <=2 wave-uniform clamped step-16 blocks,
// padded lanes hit the L1-resident zero row.
__global__ void __launch_bounds__(256)
mean_agg_kernel(const uint4* __restrict__ tbl4,
                const int* __restrict__ nids,
                const int* __restrict__ row_start,
                float* __restrict__ out,
                int n_rows, int zero_row) {
    int wave = (blockIdx.x * blockDim.x + threadIdx.x) >> 6;
    int lane = threadIdx.x & (WAVE - 1);
    if (wave >= n_rows) return;

    const int q   = lane >> 4;     // quarter 0..3 -> which edge of a group of 4
    const int sub = lane & 15;     // uint4 slot within the 256 B row

    int lo = row_start[wave];
    int hi = row_start[wave + 1];

    float acc[8];
    #pragma unroll
    for (int k = 0; k < 8; ++k) acc[k] = 0.f;

    int e = lo;
    // full loop: 32 edges, ids via one wave load + shuffle, 8 gathers in flight
    for (; e + 32 <= hi; e += 32) {
        int myid = nids[e + (lane & 31)];
        uint4 u[8];
        #pragma unroll
        for (int g = 0; g < 8; ++g) {
            int nid = __shfl(myid, 4 * g + q, WAVE);
            u[g] = tbl4[((unsigned)nid << 4) + (unsigned)sub];
        }
        #pragma unroll
        for (int g = 0; g < 8; ++g) {
            acc[0] += __uint_as_float(u[g].x << 16);
            acc[1] += __uint_as_float(u[g].x & 0xffff0000u);
            acc[2] += __uint_as_float(u[g].y << 16);
            acc[3] += __uint_as_float(u[g].y & 0xffff0000u);
            acc[4] += __uint_as_float(u[g].z << 16);
            acc[5] += __uint_as_float(u[g].z & 0xffff0000u);
            acc[6] += __uint_as_float(u[g].w << 16);
            acc[7] += __uint_as_float(u[g].w & 0xffff0000u);
        }
    }
    // remainder: up to 2 clamped step-16 blocks (wave-uniform branches)
    #pragma unroll
    for (int half_blk = 0; half_blk < 2; ++half_blk) {
        if (e < hi) {
            #pragma unroll
            for (int g = 0; g < 4; ++g) {
                int idx = e + 4 * g + q;
                int idc = idx < hi ? idx : hi - 1;
                int nid = nids[idc];
                nid = idx < hi ? nid : zero_row;
                uint4 u = tbl4[((unsigned)nid << 4) + (unsigned)sub];
                acc[0] += __uint_as_float(u.x << 16);
                acc[1] += __uint_as_float(u.x & 0xffff0000u);
                acc[2] += __uint_as_float(u.y << 16);
                acc[3] += __uint_as_float(u.y & 0xffff0000u);
                acc[4] += __uint_as_float(u.z << 16);
                acc[5] += __uint_as_float(u.z & 0xffff0000u);
                acc[6] += __uint_as_float(u.w << 16);
                acc[7] += __uint_as_float(u.w & 0xffff0000u);
            }
            e += 16;
        }
    }

    // fold the four quarter-wave accumulators (xor 16, then 32)
    #pragma unroll
    for (int k = 0; k < 8; ++k) {
        acc[k] += __shfl_xor(acc[k], 16, WAVE);
        acc[k] += __shfl_xor(acc[k], 32, WAVE);
    }

    int deg = hi - lo;
    float inv = 1.0f / (float)(deg > 0 ? deg : 1);

    // lanes 0-31 each store one float4 -> one coalesced 512 B row write
    if (q < 2) {
        float4 o;
        o.x = (q == 0 ? acc[0] : acc[4]) * inv;
        o.y = (q == 0 ? acc[1] : acc[5]) * inv;
        o.z = (q == 0 ? acc[2] : acc[6]) * inv;
        o.w = (q == 0 ? acc[3] : acc[7]) * inv;
        *(float4*)(out + (size_t)wave * D_FEAT + sub * 8 + q * 4) = o;
    }
}

extern "C" void kernel_launch(void* const* d_in, const int* in_sizes, int n_in,
                              void* d_out, int out_size, void* d_ws, size_t ws_size,
                              hipStream_t stream) {
    const float* feats = (const float*)d_in[0];
    const int* nids    = (const int*)d_in[1];
    const int* rids    = (const int*)d_in[2];
    float* out         = (float*)d_out;

    int n_feat_elems = in_sizes[0];
    int n_nodes      = n_feat_elems / D_FEAT;
    int n_edges      = in_sizes[1];
    int n_rows       = out_size / D_FEAT;

    // ws layout: [bf16 table, (n_nodes+1) rows incl. zero row][row_start]
    unsigned short* tbl = (unsigned short*)d_ws;
    size_t tbl_bytes = (size_t)(n_nodes + 1) * D_FEAT * sizeof(unsigned short);
    tbl_bytes = (tbl_bytes + 255) & ~(size_t)255;
    int* row_start = (int*)((char*)d_ws + tbl_bytes);

    const int BLOCK = 256;

    int total_tbl = (n_nodes + 1) * D_FEAT;
    int grid_c = ((total_tbl + 7) / 8 + BLOCK - 1) / BLOCK;
    int grid_b = (n_edges + BLOCK - 1) / BLOCK;
    prep_kernel<<<grid_c + grid_b, BLOCK, 0, stream>>>(feats, tbl, n_feat_elems,
                                                       total_tbl, rids, row_start,
                                                       n_edges, n_rows, grid_c);

    int waves_per_block = BLOCK / WAVE;
    int grid_a = (n_rows + waves_per_block - 1) / waves_per_block;
    mean_agg_kernel<<<grid_a, BLOCK, 0, stream>>>((const uint4*)tbl, nids, row_start,
                                                  out, n_rows, n_nodes);
}